// Round 9
// baseline (1839.828 us; speedup 1.0000x reference)
//
#include <hip/hip_runtime.h>

// ============================================================================
// CapsuleNet forward. Round 9:
//  - fused_conv + repack_b reverted VERBATIM to round 6 (592 us, no spill).
//    r7/r8 pipelining attempts both spilled (WRITE 0.5-1.4 GB scratch).
//  - routing_a redesigned: block = (18-cap chunk, 128-image group); caps_w
//    slice lives in LDS (92 KB) and is reused across 128 images -> cwt
//    traffic 3 GB -> 24 MB per pass (was L2-BW-bound at ~120 us/pass).
//    Grid = 64 x 4 = 256 blocks = 1/CU. uhat rows padded to 161 (bank).
//    s_part[64][512][160] aliases dead bph/bpl; repack_cw deleted.
// ============================================================================

#define N_IMG 512
#define CAPC 18  // caps per routing chunk (1152 = 64 * 18)

typedef __attribute__((ext_vector_type(8))) short bf16x8;
typedef __attribute__((ext_vector_type(4))) float f32x4;
typedef __attribute__((ext_vector_type(4))) unsigned int u32x4;

__device__ __forceinline__ unsigned short f2bf(float v) {
  unsigned int uu = __float_as_uint(v);
  uu += 0x7FFF + ((uu >> 16) & 1);
  return (unsigned short)(uu >> 16);
}
__device__ __forceinline__ float bf2f(unsigned short h) {
  return __uint_as_float(((unsigned int)h) << 16);
}
__device__ __forceinline__ int swz16(int row) {  // byte offset of 16B A-row
  return (row ^ ((row >> 3) & 7)) << 4;
}

// ---------------------------------------------------------------------------
// repack conv2 weights w2[256co][256ci][81rs] -> B-fragment order (hi/lo):
// Bp[n 16][ktile 656][lane 64][8], ktile = c*41+tt, rs = 2tt+lh padded to 82.
// ---------------------------------------------------------------------------
__global__ __launch_bounds__(256) void repack_b_kernel(
    const float* __restrict__ w2, unsigned short* __restrict__ bph,
    unsigned short* __restrict__ bpl) {
  __shared__ float slab[82 * 16 * 17];  // [rs][co][ci pad 17]
  const int n = blockIdx.x, c = blockIdx.y;
  const int tid = threadIdx.x;
  for (int e = tid; e < 81 * 256; e += 256) {
    const int row = e / 81;
    const int rs = e - row * 81;
    const int co = row >> 4, ci = row & 15;
    slab[(rs * 16 + co) * 17 + ci] =
        w2[((size_t)(n * 16 + co) * 256 + c * 16 + ci) * 81 + rs];
  }
  __syncthreads();
  const int lane = tid & 63;
  const int l15 = lane & 15;
  const int lh = lane >> 5;
  const int cio8 = ((lane >> 4) & 1) * 8;
  for (int tt = tid >> 6; tt < 41; tt += 4) {
    const int rs = 2 * tt + lh;
    unsigned int hw[4], lw[4];
#pragma unroll
    for (int jp = 0; jp < 4; ++jp) {
      unsigned short h2[2], l2[2];
#pragma unroll
      for (int e = 0; e < 2; ++e) {
        const int j = jp * 2 + e;
        float v = (rs < 81) ? slab[(rs * 16 + l15) * 17 + cio8 + j] : 0.0f;
        unsigned short hh = f2bf(v);
        h2[e] = hh;
        l2[e] = f2bf(v - bf2f(hh));
      }
      hw[jp] = (unsigned int)h2[0] | ((unsigned int)h2[1] << 16);
      lw[jp] = (unsigned int)l2[0] | ((unsigned int)l2[1] << 16);
    }
    const size_t off = (((size_t)n * 656 + c * 41 + tt) * 64 + lane) * 8;
    *(u32x4*)(bph + off) = (u32x4){hw[0], hw[1], hw[2], hw[3]};
    *(u32x4*)(bpl + off) = (u32x4){lw[0], lw[1], lw[2], lw[3]};
  }
}

// ---------------------------------------------------------------------------
// conv1 half-row worker (round-6): 10 outputs at ox' = H*10 + (0..9).
// ---------------------------------------------------------------------------
template <int H>
__device__ __forceinline__ void conv1_half(const float* __restrict__ ib,
                                           const float* __restrict__ w1l,
                                           float* __restrict__ stg, int ch,
                                           int oy, float bv1) {
  float a[10];
#pragma unroll
  for (int ox = 0; ox < 10; ++ox) a[ox] = bv1;
#pragma unroll
  for (int r = 0; r < 9; ++r) {
    float row[20];
    const float4* rp = (const float4*)&ib[(oy + r) * 28 + H * 8];
#pragma unroll
    for (int q = 0; q < 5; ++q) {
      float4 v4 = rp[q];
      row[4 * q + 0] = v4.x; row[4 * q + 1] = v4.y;
      row[4 * q + 2] = v4.z; row[4 * q + 3] = v4.w;
    }
#pragma unroll
    for (int s = 0; s < 9; ++s) {
      const float wval = w1l[ch * 81 + r * 9 + s];
#pragma unroll
      for (int ox = 0; ox < 10; ++ox)
        a[ox] = fmaf(row[ox + s + 2 * H], wval, a[ox]);
    }
  }
  float2* dst = (float2*)&stg[oy * 20 + H * 10];
#pragma unroll
  for (int q = 0; q < 5; ++q) {
    float2 v2;
    v2.x = fmaxf(a[2 * q + 0], 0.0f);
    v2.y = fmaxf(a[2 * q + 1], 0.0f);
    dst[q] = v2;
  }
}

// ---------------------------------------------------------------------------
// Fused conv1 -> hi/lo A (swizzled) -> MFMA conv2 (k-split, depth-2 B
// prefetch) -> squash.  VERBATIM round 6 (592 us, VGPR 120, no spill).
// ---------------------------------------------------------------------------
__global__ __launch_bounds__(512, 1) void fused_conv_kernel(
    const float* __restrict__ x, const float* __restrict__ w1,
    const float* __restrict__ b1, const unsigned short* __restrict__ bph,
    const unsigned short* __restrict__ bpl, const float* __restrict__ b2,
    float* __restrict__ u) {
  __shared__ __align__(16) char smem[115008];
  float* stg = (float*)(smem + 51776);   // [2][16][404]
  float* img = (float*)(smem + 103488);  // [2][784]
  float* w1l = (float*)(smem + 109760);  // [16*81]
  float* b1l = (float*)(smem + 114944);  // [16]
  float* mrg = (float*)smem;
  float* sq = (float*)smem;

  const int bp2 = blockIdx.x;
  const int tid = threadIdx.x;
  const int wid = tid >> 6;
  const int g = wid & 3;
  const int kpar = wid >> 2;
  const int lane = tid & 63;
  const int l15 = lane & 15;
  const int lq4 = lane >> 4;
  const int lqb = lq4 & 1;
  const int lh = lane >> 5;

  int rowb[5];
  bool okm[5];
#pragma unroll
  for (int mt = 0; mt < 5; ++mt) {
    const int m = mt * 16 + l15;
    okm[mt] = (m < 72);
    const int mm = okm[mt] ? m : 0;
    const int im = (mm >= 36) ? 1 : 0;
    const int p = mm - 36 * im;
    const int oy = p / 6, ox = p - 6 * oy;
    rowb[mt] = im * 400 + 40 * oy + 2 * ox;
  }

  for (int i = tid; i < 1568; i += 512) img[i] = x[bp2 * 1568 + i];
  if (tid < 16) {  // zero pad-slot 800 (swz 804) in all 4 arrays
    *(int*)(smem + (tid >> 2) * 12944 + 804 * 16 + (tid & 3) * 4) = 0;
  }

  f32x4 acc[5][4];
#pragma unroll
  for (int mt = 0; mt < 5; ++mt)
#pragma unroll
    for (int nn = 0; nn < 4; ++nn) acc[mt][nn] = (f32x4){0.f, 0.f, 0.f, 0.f};

  const char* hbase = smem + lqb * 12944;
  const char* lbase = smem + 25888 + lqb * 12944;
  const int tt0 = kpar ? 21 : 0;
  const int tt1 = kpar ? 41 : 21;
  const int nk = tt1 - tt0;

#define MFMA_STEP(CBH, CBL, J, DOPF)                                       \
  {                                                                        \
    const int rs_ = 2 * (tt0 + (J)) + lh;                                  \
    const int r_ = (rs_ * 57) >> 9;                                        \
    const int s_ = rs_ - 9 * r_;                                           \
    const int rs20_ = 20 * r_ + s_;                                        \
    const bool okrs_ = (rs_ <= 80);                                        \
    bf16x8 ah[5], al[5];                                                   \
    _Pragma("unroll") for (int mt = 0; mt < 5; ++mt) {                     \
      const int row_ = (okm[mt] && okrs_) ? (rowb[mt] + rs20_) : 800;      \
      const int ad_ = swz16(row_);                                         \
      ah[mt] = *(const bf16x8*)(hbase + ad_);                              \
      al[mt] = *(const bf16x8*)(lbase + ad_);                              \
    }                                                                      \
    _Pragma("unroll") for (int mt = 0; mt < 5; ++mt) {                     \
      _Pragma("unroll") for (int nn = 0; nn < 4; ++nn) {                   \
        acc[mt][nn] = __builtin_amdgcn_mfma_f32_16x16x32_bf16(             \
            al[mt], CBH[nn], acc[mt][nn], 0, 0, 0);                        \
        acc[mt][nn] = __builtin_amdgcn_mfma_f32_16x16x32_bf16(             \
            ah[mt], CBL[nn], acc[mt][nn], 0, 0, 0);                        \
        acc[mt][nn] = __builtin_amdgcn_mfma_f32_16x16x32_bf16(             \
            ah[mt], CBH[nn], acc[mt][nn], 0, 0, 0);                        \
      }                                                                    \
    }                                                                      \
    if ((DOPF) && (J) + 2 < nk) {                                          \
      _Pragma("unroll") for (int nn = 0; nn < 4; ++nn) {                   \
        CBH[nn] = *(const bf16x8*)(pb[nn] + (size_t)((J) + 2) * 512);      \
        CBL[nn] = *(const bf16x8*)(pl[nn] + (size_t)((J) + 2) * 512);      \
      }                                                                    \
    }                                                                      \
  }

#pragma unroll 1
  for (int c = 0; c < 16; ++c) {
    const unsigned short* pb[4];
    const unsigned short* pl[4];
#pragma unroll
    for (int nn = 0; nn < 4; ++nn) {
      const size_t base =
          ((size_t)(g * 4 + nn) * 656 + c * 41 + tt0) * 512 + lane * 8;
      pb[nn] = bph + base;
      pl[nn] = bpl + base;
    }
    bf16x8 cbh0[4], cbl0[4], cbh1[4], cbl1[4];
#pragma unroll
    for (int nn = 0; nn < 4; ++nn) {
      cbh0[nn] = *(const bf16x8*)(pb[nn]);
      cbl0[nn] = *(const bf16x8*)(pl[nn]);
      cbh1[nn] = *(const bf16x8*)(pb[nn] + 512);
      cbl1[nn] = *(const bf16x8*)(pl[nn] + 512);
    }

    __syncthreads();
    for (int i = tid; i < 1296; i += 512) w1l[i] = w1[c * 1296 + i];
    if (tid < 16) b1l[tid] = b1[c * 16 + tid];
    __syncthreads();

    for (int t = tid; t < 1280; t += 512) {
      const int half = (t >= 640) ? 1 : 0;
      const int rest = t - half * 640;
      const int ig = rest / 320;
      const int r2 = rest - ig * 320;
      const int ch = r2 & 15;
      const int oy = r2 >> 4;
      const float* ib = &img[ig * 784];
      float* sb = &stg[(ig * 16 + ch) * 404];
      const float bv1 = b1l[ch];
      if (half == 0)
        conv1_half<0>(ib, w1l, sb, ch, oy, bv1);
      else
        conv1_half<1>(ib, w1l, sb, ch, oy, bv1);
    }
    __syncthreads();

    for (int t = tid; t < 800; t += 512) {
      const int ig = t / 400;
      const int pos = t - ig * 400;
      const int ad = swz16(t);
      unsigned int hw[8], lw[8];
#pragma unroll
      for (int jp = 0; jp < 8; ++jp) {
        unsigned short h2[2], l2[2];
#pragma unroll
        for (int e = 0; e < 2; ++e) {
          const float v = stg[(ig * 16 + jp * 2 + e) * 404 + pos];
          const unsigned short hh = f2bf(v);
          h2[e] = hh;
          l2[e] = f2bf(v - bf2f(hh));
        }
        hw[jp] = (unsigned int)h2[0] | ((unsigned int)h2[1] << 16);
        lw[jp] = (unsigned int)l2[0] | ((unsigned int)l2[1] << 16);
      }
      *(u32x4*)(smem + ad) = (u32x4){hw[0], hw[1], hw[2], hw[3]};
      *(u32x4*)(smem + 12944 + ad) = (u32x4){hw[4], hw[5], hw[6], hw[7]};
      *(u32x4*)(smem + 25888 + ad) = (u32x4){lw[0], lw[1], lw[2], lw[3]};
      *(u32x4*)(smem + 38832 + ad) = (u32x4){lw[4], lw[5], lw[6], lw[7]};
    }
    __syncthreads();

    int j = 0;
#pragma unroll 1
    for (; j + 1 < nk; j += 2) {
      MFMA_STEP(cbh0, cbl0, j, 1);
      MFMA_STEP(cbh1, cbl1, j + 1, 1);
    }
    if (j < nk) MFMA_STEP(cbh0, cbl0, j, 0);
  }
#undef MFMA_STEP

  __syncthreads();
  if (kpar == 1) {
#pragma unroll
    for (int mt = 0; mt < 5; ++mt)
#pragma unroll
      for (int nn = 0; nn < 4; ++nn)
        *(f32x4*)(mrg + ((((g * 5 + mt) * 4 + nn) * 64 + lane) << 2)) =
            acc[mt][nn];
  }
  __syncthreads();
  if (kpar == 0) {
#pragma unroll
    for (int mt = 0; mt < 5; ++mt)
#pragma unroll
      for (int nn = 0; nn < 4; ++nn)
        acc[mt][nn] +=
            *(const f32x4*)(mrg + ((((g * 5 + mt) * 4 + nn) * 64 + lane) << 2));
  }
  __syncthreads();
  if (kpar == 0) {
    float b2v[4];
#pragma unroll
    for (int nn = 0; nn < 4; ++nn) b2v[nn] = b2[(g * 4 + nn) * 16 + l15];
#pragma unroll
    for (int mt = 0; mt < 5; ++mt) {
#pragma unroll
      for (int i = 0; i < 4; ++i) {
        const int m = mt * 16 + lq4 * 4 + i;
        if (m < 72) {
          const int im = (m >= 36) ? 1 : 0;
          const int p36 = m - 36 * im;
#pragma unroll
          for (int nn = 0; nn < 4; ++nn) {
            sq[(im * 256 + (g * 4 + nn) * 16 + l15) * 36 + p36] =
                acc[mt][nn][i] + b2v[nn];
          }
        }
      }
    }
  }
  __syncthreads();

  for (int i = tid; i < 2304; i += 512) {
    const int ig = i / 1152;
    const int cap = i - ig * 1152;
    const int gg = cap / 36, yx = cap - 36 * gg;
    float vals[8];
    float lensq = 0.0f;
#pragma unroll
    for (int d = 0; d < 8; ++d) {
      vals[d] = sq[(ig * 256 + gg * 8 + d) * 36 + yx];
      lensq = fmaf(vals[d], vals[d], lensq);
    }
    const float len = sqrtf(lensq);
    const float scale = lensq / (1.0f + lensq) / len;
    float4* dst = (float4*)(u + ((size_t)(bp2 * 2 + ig) * 1152 + cap) * 8);
    float4 lo4, hi4;
    lo4.x = vals[0] * scale; lo4.y = vals[1] * scale;
    lo4.z = vals[2] * scale; lo4.w = vals[3] * scale;
    hi4.x = vals[4] * scale; hi4.y = vals[5] * scale;
    hi4.z = vals[6] * scale; hi4.w = vals[7] * scale;
    dst[0] = lo4; dst[1] = hi4;
  }
}

// ---------------------------------------------------------------------------
// routing pass A (new): block = (chunk of 18 caps, group of 128 images).
// caps_w slice [18][8][160] staged ONCE in LDS (92 KB) and reused across all
// 128 images -> caps_w global traffic ~24 MB/pass (was ~3 GB via L2).
// Per image: u_hat (LDS, rows padded to 161), 18-thread b+softmax
// (b = b_prior + uhat.vsum by linearity), 160-thread partial s -> s_part.
// ---------------------------------------------------------------------------
__global__ __launch_bounds__(512) void routing_a_kernel(
    const float* __restrict__ u, const float* __restrict__ cw,
    const float* __restrict__ b_prior, const float* __restrict__ vsum,
    float* __restrict__ s_part, int pass) {
  __shared__ float wsl[CAPC * 1280];     // 92160 B: [cap][k 8][od 160]
  __shared__ float uhat[CAPC * 161];     // rows padded (bank spread)
  __shared__ float u_l[CAPC * 8];
  __shared__ float bp_l[CAPC * 10];
  __shared__ float c_l[CAPC * 10];
  __shared__ float v_l[160];

  const int ig = blockIdx.x;  // image group (128 images)
  const int ch = blockIdx.y;  // capsule chunk (0..63)
  const int cap0 = ch * CAPC;
  const int tid = threadIdx.x;

  {
    const float4* src = (const float4*)(cw + (size_t)cap0 * 1280);
    for (int i = tid; i < CAPC * 320; i += 512) ((float4*)wsl)[i] = src[i];
  }
  if (tid < CAPC * 10) bp_l[tid] = b_prior[cap0 * 10 + tid];
  __syncthreads();

#pragma unroll 1
  for (int im = 0; im < 128; ++im) {
    const int b = ig * 128 + im;
    if (tid < CAPC * 8) u_l[tid] = u[((size_t)b * 1152 + cap0) * 8 + tid];
    if (pass > 0 && tid >= 256 && tid < 416)
      v_l[tid - 256] = vsum[b * 160 + (tid - 256)];
    __syncthreads();

    // u_hat[cap][od] = dot8(u[cap], w[cap][.][od])
    for (int e = tid; e < CAPC * 160; e += 512) {
      const int cap = e / 160, od = e - 160 * cap;
      const float* wp = &wsl[cap * 1280 + od];
      const float* up = &u_l[cap * 8];
      float a = up[0] * wp[0];
      a = fmaf(up[1], wp[160], a);
      a = fmaf(up[2], wp[320], a);
      a = fmaf(up[3], wp[480], a);
      a = fmaf(up[4], wp[640], a);
      a = fmaf(up[5], wp[800], a);
      a = fmaf(up[6], wp[960], a);
      a = fmaf(up[7], wp[1120], a);
      uhat[cap * 161 + od] = a;
    }
    __syncthreads();

    // b = b_prior (+ uhat.vsum), softmax over o — one thread per capsule
    if (tid < CAPC) {
      float bb[10];
      float m = -1e30f;
#pragma unroll
      for (int o = 0; o < 10; ++o) {
        float v = bp_l[tid * 10 + o];
        if (pass > 0) {
          float agg = 0.0f;
#pragma unroll
          for (int d = 0; d < 16; ++d)
            agg = fmaf(uhat[tid * 161 + o * 16 + d], v_l[o * 16 + d], agg);
          v += agg;
        }
        bb[o] = v;
        m = fmaxf(m, v);
      }
      float sum = 0.0f;
#pragma unroll
      for (int o = 0; o < 10; ++o) {
        bb[o] = __expf(bb[o] - m);
        sum += bb[o];
      }
      const float inv = 1.0f / sum;
#pragma unroll
      for (int o = 0; o < 10; ++o) c_l[tid * 10 + o] = bb[o] * inv;
    }
    __syncthreads();

    // partial s over this chunk's 18 capsules
    if (tid < 160) {
      const int o = tid >> 4;
      float a = 0.0f;
#pragma unroll
      for (int cap = 0; cap < CAPC; ++cap)
        a = fmaf(c_l[cap * 10 + o], uhat[cap * 161 + tid], a);
      s_part[((size_t)ch * N_IMG + b) * 160 + tid] = a;
    }
    __syncthreads();
  }
}

// ---------------------------------------------------------------------------
// routing pass B: reduce 64 partials -> squash -> v, probs; vsum mode.
// ---------------------------------------------------------------------------
__global__ __launch_bounds__(192) void routing_b_kernel(
    const float* __restrict__ s_part, float* __restrict__ v_out,
    float* __restrict__ probs, float* __restrict__ vsum, int mode) {
  __shared__ float s_l[160];
  __shared__ float scale_l[10];
  __shared__ float len_l[10];
  const int b = blockIdx.x;
  const int t = threadIdx.x;
  if (t < 160) {
    float a = 0.0f;
#pragma unroll
    for (int ch = 0; ch < 64; ++ch)
      a += s_part[((size_t)ch * N_IMG + b) * 160 + t];
    s_l[t] = a;
  }
  __syncthreads();
  if (t < 10) {
    float lensq = 0.0f;
#pragma unroll
    for (int d = 0; d < 16; ++d) {
      const float xv = s_l[t * 16 + d];
      lensq = fmaf(xv, xv, lensq);
    }
    const float len = sqrtf(lensq);
    scale_l[t] = lensq / (1.0f + lensq) / len;
    len_l[t] = lensq / (1.0f + lensq);
  }
  __syncthreads();
  if (t < 160) {
    const float vv = s_l[t] * scale_l[t / 16];
    v_out[b * 160 + t] = vv;
    if (mode == 0) vsum[b * 160 + t] = vv;
    else if (mode == 1) vsum[b * 160 + t] += vv;
  }
  if (t < 10) probs[b * 10 + t] = len_l[t];
}

// ===========================================================================
extern "C" void kernel_launch(void* const* d_in, const int* in_sizes, int n_in,
                              void* d_out, int out_size, void* d_ws,
                              size_t ws_size, hipStream_t stream) {
  const float* x  = (const float*)d_in[0];
  const float* w1 = (const float*)d_in[1];
  const float* b1 = (const float*)d_in[2];
  const float* w2 = (const float*)d_in[3];
  const float* b2 = (const float*)d_in[4];
  const float* cw = (const float*)d_in[5];
  const float* bp = (const float*)d_in[6];

  float* out = (float*)d_out;
  float* v_out = out;                // [512,10,16]
  float* probs = out + N_IMG * 160;  // [512,10]

  unsigned short* bph = (unsigned short*)d_ws;         // 10.75 MB
  unsigned short* bpl = bph + (size_t)16 * 656 * 512;  // 10.75 MB
  float* u    = (float*)d_ws + 2 * 2686976;            // 18.9 MB
  float* vsum = u + (size_t)N_IMG * 1152 * 8;          //  0.33 MB
  // s_part[64][512][160] = 20.97 MB aliases bph+bpl (dead after fused_conv)
  float* sp = (float*)d_ws;

  repack_b_kernel<<<dim3(16, 16), 256, 0, stream>>>(w2, bph, bpl);
  fused_conv_kernel<<<256, 512, 0, stream>>>(x, w1, b1, bph, bpl, b2, u);
  for (int pass = 0; pass < 4; ++pass) {
    const int mode = (pass == 0) ? 0 : (pass < 3 ? 1 : 2);
    routing_a_kernel<<<dim3(4, 64), 512, 0, stream>>>(u, cw, bp, vsum, sp,
                                                      pass);
    routing_b_kernel<<<N_IMG, 192, 0, stream>>>(sp, v_out, probs, vsum, mode);
  }
}

// Round 12
// 1103.624 us; speedup vs baseline: 1.6671x; 1.6671x over previous
//
#include <hip/hip_runtime.h>

// ============================================================================
// CapsuleNet forward. Round 12: r11 structure verified fast (1105 us) but had
// a RACE in gemm_s0_kernel: c0_l[320] staged by `if (tid<320)` with only 256
// threads -> entries 256..319 uninitialized (nondeterministic post-timing
// divergence). Fixed with a strided staging loop. Everything else = r11:
//  - conv path (repack_b + fused_conv): r6/r9 verbatim (592 us verified).
//  - pass 0 as GEMM (c0 = softmax(b_prior) is image-independent).
//  - passes 1-3: r5-exact fp32 routing_a (119 us/pass verified).
// ============================================================================

#define N_IMG 512

typedef __attribute__((ext_vector_type(8))) short bf16x8;
typedef __attribute__((ext_vector_type(4))) float f32x4;
typedef __attribute__((ext_vector_type(4))) unsigned int u32x4;

__device__ __forceinline__ unsigned short f2bf(float v) {
  unsigned int uu = __float_as_uint(v);
  uu += 0x7FFF + ((uu >> 16) & 1);
  return (unsigned short)(uu >> 16);
}
__device__ __forceinline__ float bf2f(unsigned short h) {
  return __uint_as_float(((unsigned int)h) << 16);
}
__device__ __forceinline__ int swz16(int row) {  // byte offset of 16B A-row
  return (row ^ ((row >> 3) & 7)) << 4;
}

// ---------------------------------------------------------------------------
// repack conv2 weights w2[256co][256ci][81rs] -> B-fragment order (hi/lo).
// ---------------------------------------------------------------------------
__global__ __launch_bounds__(256) void repack_b_kernel(
    const float* __restrict__ w2, unsigned short* __restrict__ bph,
    unsigned short* __restrict__ bpl) {
  __shared__ float slab[82 * 16 * 17];  // [rs][co][ci pad 17]
  const int n = blockIdx.x, c = blockIdx.y;
  const int tid = threadIdx.x;
  for (int e = tid; e < 81 * 256; e += 256) {
    const int row = e / 81;
    const int rs = e - row * 81;
    const int co = row >> 4, ci = row & 15;
    slab[(rs * 16 + co) * 17 + ci] =
        w2[((size_t)(n * 16 + co) * 256 + c * 16 + ci) * 81 + rs];
  }
  __syncthreads();
  const int lane = tid & 63;
  const int l15 = lane & 15;
  const int lh = lane >> 5;
  const int cio8 = ((lane >> 4) & 1) * 8;
  for (int tt = tid >> 6; tt < 41; tt += 4) {
    const int rs = 2 * tt + lh;
    unsigned int hw[4], lw[4];
#pragma unroll
    for (int jp = 0; jp < 4; ++jp) {
      unsigned short h2[2], l2[2];
#pragma unroll
      for (int e = 0; e < 2; ++e) {
        const int j = jp * 2 + e;
        float v = (rs < 81) ? slab[(rs * 16 + l15) * 17 + cio8 + j] : 0.0f;
        unsigned short hh = f2bf(v);
        h2[e] = hh;
        l2[e] = f2bf(v - bf2f(hh));
      }
      hw[jp] = (unsigned int)h2[0] | ((unsigned int)h2[1] << 16);
      lw[jp] = (unsigned int)l2[0] | ((unsigned int)l2[1] << 16);
    }
    const size_t off = (((size_t)n * 656 + c * 41 + tt) * 64 + lane) * 8;
    *(u32x4*)(bph + off) = (u32x4){hw[0], hw[1], hw[2], hw[3]};
    *(u32x4*)(bpl + off) = (u32x4){lw[0], lw[1], lw[2], lw[3]};
  }
}

// ---------------------------------------------------------------------------
// transpose caps_w [1152][8][160] -> fp32 cw_t [1152][160][8] (r5-exact).
// ---------------------------------------------------------------------------
__global__ __launch_bounds__(160) void repack_cw_kernel(
    const float* __restrict__ cw, float* __restrict__ cwt) {
  __shared__ float t[8][160];
  const int i = blockIdx.x;
  const int od = threadIdx.x;
#pragma unroll
  for (int k = 0; k < 8; ++k) t[k][od] = cw[((size_t)i * 8 + k) * 160 + od];
  __syncthreads();
  float4 o0 = {t[0][od], t[1][od], t[2][od], t[3][od]};
  float4 o1 = {t[4][od], t[5][od], t[6][od], t[7][od]};
  float4* dst = (float4*)(cwt + ((size_t)i * 160 + od) * 8);
  dst[0] = o0;
  dst[1] = o1;
}

// ---------------------------------------------------------------------------
// c0 = softmax(b_prior) per capsule (image-independent).
// ---------------------------------------------------------------------------
__global__ __launch_bounds__(256) void c0_kernel(const float* __restrict__ bp,
                                                 float* __restrict__ c0b) {
  const int i = blockIdx.x * 256 + threadIdx.x;
  if (i >= 1152) return;
  float b[10];
  float m = -1e30f;
#pragma unroll
  for (int o = 0; o < 10; ++o) {
    b[o] = bp[i * 10 + o];
    m = fmaxf(m, b[o]);
  }
  float sum = 0.0f;
#pragma unroll
  for (int o = 0; o < 10; ++o) {
    b[o] = __expf(b[o] - m);
    sum += b[o];
  }
  const float inv = 1.0f / sum;
#pragma unroll
  for (int o = 0; o < 10; ++o) c0b[i * 10 + o] = b[o] * inv;
}

// ---------------------------------------------------------------------------
// Pass-0 GEMM: s0[b][od] = sum_{i,k} u[b,i,k] * c0[i][od/16] * cw[i][k][od].
// Grid (8 Mtiles x 36 Ksplits), 256 thr. Block: 64 images x 160 od over a
// K-slice of 256 (32 caps). A in LDS (rows padded to 257), B chunked 64xK in
// LDS (c0-scaled at staging). Thread tile 4x10 (register-blocked).
// Output partials s0p[ks][b][od]; reduced by routing_b (nchunk=36).
// RACE FIX (r12): c0_l staged with a strided loop (320 > 256 threads).
// ---------------------------------------------------------------------------
__global__ __launch_bounds__(256) void gemm_s0_kernel(
    const float* __restrict__ u, const float* __restrict__ cw,
    const float* __restrict__ c0b, float* __restrict__ s0p) {
  __shared__ float a_l[64 * 257];
  __shared__ float b_l[64 * 160];
  __shared__ float c0_l[320];
  const int mt = blockIdx.x;   // 0..7
  const int ks = blockIdx.y;   // 0..35
  const int m0 = mt * 64;
  const int tid = threadIdx.x;
  const int mb = tid >> 4;          // 0..15 -> rows mb*4..mb*4+3
  const int ob = (tid & 15) * 10;   // cols ob..ob+9

  for (int i = tid; i < 320; i += 256) c0_l[i] = c0b[(ks * 32) * 10 + i];
  for (int idx = tid; idx < 16384; idx += 256) {
    const int m = idx >> 8, kk = idx & 255;
    a_l[m * 257 + kk] = u[(size_t)(m0 + m) * 9216 + ks * 256 + kk];
  }

  float acc[4][10];
#pragma unroll
  for (int r = 0; r < 4; ++r)
#pragma unroll
    for (int c = 0; c < 10; ++c) acc[r][c] = 0.0f;

#pragma unroll 1
  for (int kc = 0; kc < 4; ++kc) {
    __syncthreads();  // a_l/c0_l ready (kc=0) or prev b_l reads done
    for (int idx = tid; idx < 10240; idx += 256) {
      const int kk = idx / 160, od = idx - kk * 160;
      const int kg = kc * 64 + kk;
      b_l[kk * 160 + od] = cw[((size_t)ks * 256 + kg) * 160 + od] *
                           c0_l[(kg >> 3) * 10 + (od >> 4)];
    }
    __syncthreads();
#pragma unroll 4
    for (int kk = 0; kk < 64; ++kk) {
      float a4[4];
#pragma unroll
      for (int r = 0; r < 4; ++r)
        a4[r] = a_l[(mb * 4 + r) * 257 + kc * 64 + kk];
      const float* bp_ = &b_l[kk * 160 + ob];
#pragma unroll
      for (int c = 0; c < 10; ++c) {
        const float bv = bp_[c];
#pragma unroll
        for (int r = 0; r < 4; ++r) acc[r][c] = fmaf(a4[r], bv, acc[r][c]);
      }
    }
  }

#pragma unroll
  for (int r = 0; r < 4; ++r) {
#pragma unroll
    for (int c = 0; c < 10; ++c) {
      s0p[((size_t)ks * N_IMG + m0 + mb * 4 + r) * 160 + ob + c] = acc[r][c];
    }
  }
}

// ---------------------------------------------------------------------------
// conv1 half-row worker (round-6): 10 outputs at ox' = H*10 + (0..9).
// ---------------------------------------------------------------------------
template <int H>
__device__ __forceinline__ void conv1_half(const float* __restrict__ ib,
                                           const float* __restrict__ w1l,
                                           float* __restrict__ stg, int ch,
                                           int oy, float bv1) {
  float a[10];
#pragma unroll
  for (int ox = 0; ox < 10; ++ox) a[ox] = bv1;
#pragma unroll
  for (int r = 0; r < 9; ++r) {
    float row[20];
    const float4* rp = (const float4*)&ib[(oy + r) * 28 + H * 8];
#pragma unroll
    for (int q = 0; q < 5; ++q) {
      float4 v4 = rp[q];
      row[4 * q + 0] = v4.x; row[4 * q + 1] = v4.y;
      row[4 * q + 2] = v4.z; row[4 * q + 3] = v4.w;
    }
#pragma unroll
    for (int s = 0; s < 9; ++s) {
      const float wval = w1l[ch * 81 + r * 9 + s];
#pragma unroll
      for (int ox = 0; ox < 10; ++ox)
        a[ox] = fmaf(row[ox + s + 2 * H], wval, a[ox]);
    }
  }
  float2* dst = (float2*)&stg[oy * 20 + H * 10];
#pragma unroll
  for (int q = 0; q < 5; ++q) {
    float2 v2;
    v2.x = fmaxf(a[2 * q + 0], 0.0f);
    v2.y = fmaxf(a[2 * q + 1], 0.0f);
    dst[q] = v2;
  }
}

// ---------------------------------------------------------------------------
// Fused conv1 -> hi/lo A (swizzled) -> MFMA conv2 (k-split, depth-2 B
// prefetch) -> squash.  VERBATIM round 6/9 (592 us, VGPR 120, no spill).
// ---------------------------------------------------------------------------
__global__ __launch_bounds__(512, 1) void fused_conv_kernel(
    const float* __restrict__ x, const float* __restrict__ w1,
    const float* __restrict__ b1, const unsigned short* __restrict__ bph,
    const unsigned short* __restrict__ bpl, const float* __restrict__ b2,
    float* __restrict__ u) {
  __shared__ __align__(16) char smem[115008];
  float* stg = (float*)(smem + 51776);   // [2][16][404]
  float* img = (float*)(smem + 103488);  // [2][784]
  float* w1l = (float*)(smem + 109760);  // [16*81]
  float* b1l = (float*)(smem + 114944);  // [16]
  float* mrg = (float*)smem;
  float* sq = (float*)smem;

  const int bp2 = blockIdx.x;
  const int tid = threadIdx.x;
  const int wid = tid >> 6;
  const int g = wid & 3;
  const int kpar = wid >> 2;
  const int lane = tid & 63;
  const int l15 = lane & 15;
  const int lq4 = lane >> 4;
  const int lqb = lq4 & 1;
  const int lh = lane >> 5;

  int rowb[5];
  bool okm[5];
#pragma unroll
  for (int mt = 0; mt < 5; ++mt) {
    const int m = mt * 16 + l15;
    okm[mt] = (m < 72);
    const int mm = okm[mt] ? m : 0;
    const int im = (mm >= 36) ? 1 : 0;
    const int p = mm - 36 * im;
    const int oy = p / 6, ox = p - 6 * oy;
    rowb[mt] = im * 400 + 40 * oy + 2 * ox;
  }

  for (int i = tid; i < 1568; i += 512) img[i] = x[bp2 * 1568 + i];
  if (tid < 16) {  // zero pad-slot 800 (swz 804) in all 4 arrays
    *(int*)(smem + (tid >> 2) * 12944 + 804 * 16 + (tid & 3) * 4) = 0;
  }

  f32x4 acc[5][4];
#pragma unroll
  for (int mt = 0; mt < 5; ++mt)
#pragma unroll
    for (int nn = 0; nn < 4; ++nn) acc[mt][nn] = (f32x4){0.f, 0.f, 0.f, 0.f};

  const char* hbase = smem + lqb * 12944;
  const char* lbase = smem + 25888 + lqb * 12944;
  const int tt0 = kpar ? 21 : 0;
  const int tt1 = kpar ? 41 : 21;
  const int nk = tt1 - tt0;

#define MFMA_STEP(CBH, CBL, J, DOPF)                                       \
  {                                                                        \
    const int rs_ = 2 * (tt0 + (J)) + lh;                                  \
    const int r_ = (rs_ * 57) >> 9;                                        \
    const int s_ = rs_ - 9 * r_;                                           \
    const int rs20_ = 20 * r_ + s_;                                        \
    const bool okrs_ = (rs_ <= 80);                                        \
    bf16x8 ah[5], al[5];                                                   \
    _Pragma("unroll") for (int mt = 0; mt < 5; ++mt) {                     \
      const int row_ = (okm[mt] && okrs_) ? (rowb[mt] + rs20_) : 800;      \
      const int ad_ = swz16(row_);                                         \
      ah[mt] = *(const bf16x8*)(hbase + ad_);                              \
      al[mt] = *(const bf16x8*)(lbase + ad_);                              \
    }                                                                      \
    _Pragma("unroll") for (int mt = 0; mt < 5; ++mt) {                     \
      _Pragma("unroll") for (int nn = 0; nn < 4; ++nn) {                   \
        acc[mt][nn] = __builtin_amdgcn_mfma_f32_16x16x32_bf16(             \
            al[mt], CBH[nn], acc[mt][nn], 0, 0, 0);                        \
        acc[mt][nn] = __builtin_amdgcn_mfma_f32_16x16x32_bf16(             \
            ah[mt], CBL[nn], acc[mt][nn], 0, 0, 0);                        \
        acc[mt][nn] = __builtin_amdgcn_mfma_f32_16x16x32_bf16(             \
            ah[mt], CBH[nn], acc[mt][nn], 0, 0, 0);                        \
      }                                                                    \
    }                                                                      \
    if ((DOPF) && (J) + 2 < nk) {                                          \
      _Pragma("unroll") for (int nn = 0; nn < 4; ++nn) {                   \
        CBH[nn] = *(const bf16x8*)(pb[nn] + (size_t)((J) + 2) * 512);      \
        CBL[nn] = *(const bf16x8*)(pl[nn] + (size_t)((J) + 2) * 512);      \
      }                                                                    \
    }                                                                      \
  }

#pragma unroll 1
  for (int c = 0; c < 16; ++c) {
    const unsigned short* pb[4];
    const unsigned short* pl[4];
#pragma unroll
    for (int nn = 0; nn < 4; ++nn) {
      const size_t base =
          ((size_t)(g * 4 + nn) * 656 + c * 41 + tt0) * 512 + lane * 8;
      pb[nn] = bph + base;
      pl[nn] = bpl + base;
    }
    bf16x8 cbh0[4], cbl0[4], cbh1[4], cbl1[4];
#pragma unroll
    for (int nn = 0; nn < 4; ++nn) {
      cbh0[nn] = *(const bf16x8*)(pb[nn]);
      cbl0[nn] = *(const bf16x8*)(pl[nn]);
      cbh1[nn] = *(const bf16x8*)(pb[nn] + 512);
      cbl1[nn] = *(const bf16x8*)(pl[nn] + 512);
    }

    __syncthreads();
    for (int i = tid; i < 1296; i += 512) w1l[i] = w1[c * 1296 + i];
    if (tid < 16) b1l[tid] = b1[c * 16 + tid];
    __syncthreads();

    for (int t = tid; t < 1280; t += 512) {
      const int half = (t >= 640) ? 1 : 0;
      const int rest = t - half * 640;
      const int ig = rest / 320;
      const int r2 = rest - ig * 320;
      const int ch = r2 & 15;
      const int oy = r2 >> 4;
      const float* ib = &img[ig * 784];
      float* sb = &stg[(ig * 16 + ch) * 404];
      const float bv1 = b1l[ch];
      if (half == 0)
        conv1_half<0>(ib, w1l, sb, ch, oy, bv1);
      else
        conv1_half<1>(ib, w1l, sb, ch, oy, bv1);
    }
    __syncthreads();

    for (int t = tid; t < 800; t += 512) {
      const int ig = t / 400;
      const int pos = t - ig * 400;
      const int ad = swz16(t);
      unsigned int hw[8], lw[8];
#pragma unroll
      for (int jp = 0; jp < 8; ++jp) {
        unsigned short h2[2], l2[2];
#pragma unroll
        for (int e = 0; e < 2; ++e) {
          const float v = stg[(ig * 16 + jp * 2 + e) * 404 + pos];
          const unsigned short hh = f2bf(v);
          h2[e] = hh;
          l2[e] = f2bf(v - bf2f(hh));
        }
        hw[jp] = (unsigned int)h2[0] | ((unsigned int)h2[1] << 16);
        lw[jp] = (unsigned int)l2[0] | ((unsigned int)l2[1] << 16);
      }
      *(u32x4*)(smem + ad) = (u32x4){hw[0], hw[1], hw[2], hw[3]};
      *(u32x4*)(smem + 12944 + ad) = (u32x4){hw[4], hw[5], hw[6], hw[7]};
      *(u32x4*)(smem + 25888 + ad) = (u32x4){lw[0], lw[1], lw[2], lw[3]};
      *(u32x4*)(smem + 38832 + ad) = (u32x4){lw[4], lw[5], lw[6], lw[7]};
    }
    __syncthreads();

    int j = 0;
#pragma unroll 1
    for (; j + 1 < nk; j += 2) {
      MFMA_STEP(cbh0, cbl0, j, 1);
      MFMA_STEP(cbh1, cbl1, j + 1, 1);
    }
    if (j < nk) MFMA_STEP(cbh0, cbl0, j, 0);
  }
#undef MFMA_STEP

  __syncthreads();
  if (kpar == 1) {
#pragma unroll
    for (int mt = 0; mt < 5; ++mt)
#pragma unroll
      for (int nn = 0; nn < 4; ++nn)
        *(f32x4*)(mrg + ((((g * 5 + mt) * 4 + nn) * 64 + lane) << 2)) =
            acc[mt][nn];
  }
  __syncthreads();
  if (kpar == 0) {
#pragma unroll
    for (int mt = 0; mt < 5; ++mt)
#pragma unroll
      for (int nn = 0; nn < 4; ++nn)
        acc[mt][nn] +=
            *(const f32x4*)(mrg + ((((g * 5 + mt) * 4 + nn) * 64 + lane) << 2));
  }
  __syncthreads();
  if (kpar == 0) {
    float b2v[4];
#pragma unroll
    for (int nn = 0; nn < 4; ++nn) b2v[nn] = b2[(g * 4 + nn) * 16 + l15];
#pragma unroll
    for (int mt = 0; mt < 5; ++mt) {
#pragma unroll
      for (int i = 0; i < 4; ++i) {
        const int m = mt * 16 + lq4 * 4 + i;
        if (m < 72) {
          const int im = (m >= 36) ? 1 : 0;
          const int p36 = m - 36 * im;
#pragma unroll
          for (int nn = 0; nn < 4; ++nn) {
            sq[(im * 256 + (g * 4 + nn) * 16 + l15) * 36 + p36] =
                acc[mt][nn][i] + b2v[nn];
          }
        }
      }
    }
  }
  __syncthreads();

  for (int i = tid; i < 2304; i += 512) {
    const int ig = i / 1152;
    const int cap = i - ig * 1152;
    const int gg = cap / 36, yx = cap - 36 * gg;
    float vals[8];
    float lensq = 0.0f;
#pragma unroll
    for (int d = 0; d < 8; ++d) {
      vals[d] = sq[(ig * 256 + gg * 8 + d) * 36 + yx];
      lensq = fmaf(vals[d], vals[d], lensq);
    }
    const float len = sqrtf(lensq);
    const float scale = lensq / (1.0f + lensq) / len;
    float4* dst = (float4*)(u + ((size_t)(bp2 * 2 + ig) * 1152 + cap) * 8);
    float4 lo4, hi4;
    lo4.x = vals[0] * scale; lo4.y = vals[1] * scale;
    lo4.z = vals[2] * scale; lo4.w = vals[3] * scale;
    hi4.x = vals[4] * scale; hi4.y = vals[5] * scale;
    hi4.z = vals[6] * scale; hi4.w = vals[7] * scale;
    dst[0] = lo4; dst[1] = hi4;
  }
}

// ---------------------------------------------------------------------------
// routing pass A (r5-exact, fp32 cwt): recompute u_hat chunk (64x160) in LDS;
// b = b_prior + uhat.vsum (linearity); softmax; partial s -> s_part.
// ---------------------------------------------------------------------------
__global__ __launch_bounds__(256) void routing_a_kernel(
    const float* __restrict__ u, const float* __restrict__ cwt,
    const float* __restrict__ b_prior, const float* __restrict__ vsum,
    float* __restrict__ s_part, int pass) {
  __shared__ float u_l[64 * 8];
  __shared__ float uhat[64 * 160];
  __shared__ float b_l[64 * 10];
  __shared__ float c_l[64 * 10];
  __shared__ float v_l[160];

  const int b = blockIdx.x;
  const int ch = blockIdx.y;
  const int cap0 = ch * 64;
  const int tid = threadIdx.x;

  {
    const float* src = u + ((size_t)b * 1152 + cap0) * 8;
    for (int i = tid; i < 512; i += 256) u_l[i] = src[i];
  }
  if (pass > 0 && tid < 160) v_l[tid] = vsum[b * 160 + tid];
  __syncthreads();

  for (int idx = tid; idx < 64 * 160; idx += 256) {
    const int i = idx / 160, od = idx - 160 * i;
    const float4* wp =
        (const float4*)(cwt + ((size_t)(cap0 + i) * 160 + od) * 8);
    const float4 wa = wp[0], wb = wp[1];
    const float4 ua = *(const float4*)&u_l[i * 8];
    const float4 ub = *(const float4*)&u_l[i * 8 + 4];
    float a = ua.x * wa.x;
    a = fmaf(ua.y, wa.y, a); a = fmaf(ua.z, wa.z, a); a = fmaf(ua.w, wa.w, a);
    a = fmaf(ub.x, wb.x, a); a = fmaf(ub.y, wb.y, a);
    a = fmaf(ub.z, wb.z, a); a = fmaf(ub.w, wb.w, a);
    uhat[idx] = a;
  }
  __syncthreads();

  for (int idx = tid; idx < 640; idx += 256) {
    const int i = idx / 10, o = idx - 10 * i;
    float bb = b_prior[(cap0 + i) * 10 + o];
    if (pass > 0) {
      float agg = 0.0f;
#pragma unroll
      for (int d = 0; d < 16; ++d)
        agg = fmaf(uhat[i * 160 + o * 16 + d], v_l[o * 16 + d], agg);
      bb += agg;
    }
    b_l[idx] = bb;
  }
  __syncthreads();

  if (tid < 64) {
    float m = -1e30f;
#pragma unroll
    for (int o = 0; o < 10; ++o) m = fmaxf(m, b_l[tid * 10 + o]);
    float e[10], sum = 0.0f;
#pragma unroll
    for (int o = 0; o < 10; ++o) {
      e[o] = __expf(b_l[tid * 10 + o] - m);
      sum += e[o];
    }
    const float inv = 1.0f / sum;
#pragma unroll
    for (int o = 0; o < 10; ++o) c_l[tid * 10 + o] = e[o] * inv;
  }
  __syncthreads();

  if (tid < 160) {
    const int o = tid / 16;
    float a = 0.0f;
    for (int i = 0; i < 64; ++i)
      a = fmaf(c_l[i * 10 + o], uhat[i * 160 + tid], a);
    s_part[((size_t)ch * N_IMG + b) * 160 + tid] = a;
  }
}

// ---------------------------------------------------------------------------
// routing pass B: reduce nchunk partials -> squash -> v, probs; vsum mode.
// ---------------------------------------------------------------------------
__global__ __launch_bounds__(192) void routing_b_kernel(
    const float* __restrict__ s_part, int nchunk, float* __restrict__ v_out,
    float* __restrict__ probs, float* __restrict__ vsum, int mode) {
  __shared__ float s_l[160];
  __shared__ float scale_l[10];
  __shared__ float len_l[10];
  const int b = blockIdx.x;
  const int t = threadIdx.x;
  if (t < 160) {
    float a = 0.0f;
    for (int ch = 0; ch < nchunk; ++ch)
      a += s_part[((size_t)ch * N_IMG + b) * 160 + t];
    s_l[t] = a;
  }
  __syncthreads();
  if (t < 10) {
    float lensq = 0.0f;
#pragma unroll
    for (int d = 0; d < 16; ++d) {
      const float xv = s_l[t * 16 + d];
      lensq = fmaf(xv, xv, lensq);
    }
    const float len = sqrtf(lensq);
    scale_l[t] = lensq / (1.0f + lensq) / len;
    len_l[t] = lensq / (1.0f + lensq);
  }
  __syncthreads();
  if (t < 160) {
    const float vv = s_l[t] * scale_l[t / 16];
    v_out[b * 160 + t] = vv;
    if (mode == 0) vsum[b * 160 + t] = vv;
    else if (mode == 1) vsum[b * 160 + t] += vv;
  }
  if (t < 10) probs[b * 10 + t] = len_l[t];
}

// ===========================================================================
extern "C" void kernel_launch(void* const* d_in, const int* in_sizes, int n_in,
                              void* d_out, int out_size, void* d_ws,
                              size_t ws_size, hipStream_t stream) {
  const float* x  = (const float*)d_in[0];
  const float* w1 = (const float*)d_in[1];
  const float* b1 = (const float*)d_in[2];
  const float* w2 = (const float*)d_in[3];
  const float* b2 = (const float*)d_in[4];
  const float* cw = (const float*)d_in[5];
  const float* bp = (const float*)d_in[6];

  float* out = (float*)d_out;
  float* v_out = out;                // [512,10,16]
  float* probs = out + N_IMG * 160;  // [512,10]

  float* base = (float*)d_ws;
  unsigned short* bph = (unsigned short*)d_ws;         // float [0, 2686976)
  unsigned short* bpl = bph + (size_t)16 * 656 * 512;  // float [2686976, 5373952)
  float* u    = base + 5373952;                        // 4718592 floats
  float* sp   = u + 4718592;                           // 1474560 floats
  float* vsum = sp + 1474560;                          // 81920 floats
  float* c0b  = vsum + 81920;                          // 11520 floats
  // Aliases into the bph/bpl region (dead after fused_conv):
  float* cwt = base;            // [0, 1474560)
  float* s0p = base + 1474560;  // [1474560, 4423680) — 36*512*160

  repack_b_kernel<<<dim3(16, 16), 256, 0, stream>>>(w2, bph, bpl);
  fused_conv_kernel<<<256, 512, 0, stream>>>(x, w1, b1, bph, bpl, b2, u);
  // pass 0 as GEMM (c0 is image-independent)
  c0_kernel<<<5, 256, 0, stream>>>(bp, c0b);
  repack_cw_kernel<<<1152, 160, 0, stream>>>(cw, cwt);
  gemm_s0_kernel<<<dim3(8, 36), 256, 0, stream>>>(u, cw, c0b, s0p);
  routing_b_kernel<<<N_IMG, 192, 0, stream>>>(s0p, 36, v_out, probs, vsum, 0);
  // passes 1..3
  for (int pass = 1; pass < 4; ++pass) {
    const int mode = (pass < 3) ? 1 : 2;
    routing_a_kernel<<<dim3(N_IMG, 18), 256, 0, stream>>>(u, cwt, bp, vsum, sp,
                                                          pass);
    routing_b_kernel<<<N_IMG, 192, 0, stream>>>(sp, 18, v_out, probs, vsum,
                                                mode);
  }
}

// Round 13
// 1016.569 us; speedup vs baseline: 1.8098x; 1.0856x over previous
//
#include <hip/hip_runtime.h>

// ============================================================================
// CapsuleNet forward. Round 13 (base = r12, 1103 us verified):
//  - conv path (repack_b + fused_conv): r6/r9 verbatim (592 us verified).
//  - pass 0 as GEMM (c0 image-independent) — r12 verbatim.
//  - routing_a passes 1-3: NEW 4-images-per-block variant. Each weight read
//    serves 4 images -> cwt L2 traffic 3 GB -> 756 MB per pass. 32-cap chunk
//    as 2x16 sub-chunks keeps uhat LDS at 41 KB (52 KB total -> 3 blocks/CU,
//    same occupancy as the 119-us r5 version). uhat rows padded to 161.
//    s_part = 36 chunks (11.8 MB) aliases the dead s0p region; ws unchanged.
// ============================================================================

#define N_IMG 512
#define RG 4  // images per routing block

typedef __attribute__((ext_vector_type(8))) short bf16x8;
typedef __attribute__((ext_vector_type(4))) float f32x4;
typedef __attribute__((ext_vector_type(4))) unsigned int u32x4;

__device__ __forceinline__ unsigned short f2bf(float v) {
  unsigned int uu = __float_as_uint(v);
  uu += 0x7FFF + ((uu >> 16) & 1);
  return (unsigned short)(uu >> 16);
}
__device__ __forceinline__ float bf2f(unsigned short h) {
  return __uint_as_float(((unsigned int)h) << 16);
}
__device__ __forceinline__ int swz16(int row) {  // byte offset of 16B A-row
  return (row ^ ((row >> 3) & 7)) << 4;
}

// ---------------------------------------------------------------------------
// repack conv2 weights w2[256co][256ci][81rs] -> B-fragment order (hi/lo).
// ---------------------------------------------------------------------------
__global__ __launch_bounds__(256) void repack_b_kernel(
    const float* __restrict__ w2, unsigned short* __restrict__ bph,
    unsigned short* __restrict__ bpl) {
  __shared__ float slab[82 * 16 * 17];  // [rs][co][ci pad 17]
  const int n = blockIdx.x, c = blockIdx.y;
  const int tid = threadIdx.x;
  for (int e = tid; e < 81 * 256; e += 256) {
    const int row = e / 81;
    const int rs = e - row * 81;
    const int co = row >> 4, ci = row & 15;
    slab[(rs * 16 + co) * 17 + ci] =
        w2[((size_t)(n * 16 + co) * 256 + c * 16 + ci) * 81 + rs];
  }
  __syncthreads();
  const int lane = tid & 63;
  const int l15 = lane & 15;
  const int lh = lane >> 5;
  const int cio8 = ((lane >> 4) & 1) * 8;
  for (int tt = tid >> 6; tt < 41; tt += 4) {
    const int rs = 2 * tt + lh;
    unsigned int hw[4], lw[4];
#pragma unroll
    for (int jp = 0; jp < 4; ++jp) {
      unsigned short h2[2], l2[2];
#pragma unroll
      for (int e = 0; e < 2; ++e) {
        const int j = jp * 2 + e;
        float v = (rs < 81) ? slab[(rs * 16 + l15) * 17 + cio8 + j] : 0.0f;
        unsigned short hh = f2bf(v);
        h2[e] = hh;
        l2[e] = f2bf(v - bf2f(hh));
      }
      hw[jp] = (unsigned int)h2[0] | ((unsigned int)h2[1] << 16);
      lw[jp] = (unsigned int)l2[0] | ((unsigned int)l2[1] << 16);
    }
    const size_t off = (((size_t)n * 656 + c * 41 + tt) * 64 + lane) * 8;
    *(u32x4*)(bph + off) = (u32x4){hw[0], hw[1], hw[2], hw[3]};
    *(u32x4*)(bpl + off) = (u32x4){lw[0], lw[1], lw[2], lw[3]};
  }
}

// ---------------------------------------------------------------------------
// transpose caps_w [1152][8][160] -> fp32 cw_t [1152][160][8].
// ---------------------------------------------------------------------------
__global__ __launch_bounds__(160) void repack_cw_kernel(
    const float* __restrict__ cw, float* __restrict__ cwt) {
  __shared__ float t[8][160];
  const int i = blockIdx.x;
  const int od = threadIdx.x;
#pragma unroll
  for (int k = 0; k < 8; ++k) t[k][od] = cw[((size_t)i * 8 + k) * 160 + od];
  __syncthreads();
  float4 o0 = {t[0][od], t[1][od], t[2][od], t[3][od]};
  float4 o1 = {t[4][od], t[5][od], t[6][od], t[7][od]};
  float4* dst = (float4*)(cwt + ((size_t)i * 160 + od) * 8);
  dst[0] = o0;
  dst[1] = o1;
}

// ---------------------------------------------------------------------------
// c0 = softmax(b_prior) per capsule (image-independent).
// ---------------------------------------------------------------------------
__global__ __launch_bounds__(256) void c0_kernel(const float* __restrict__ bp,
                                                 float* __restrict__ c0b) {
  const int i = blockIdx.x * 256 + threadIdx.x;
  if (i >= 1152) return;
  float b[10];
  float m = -1e30f;
#pragma unroll
  for (int o = 0; o < 10; ++o) {
    b[o] = bp[i * 10 + o];
    m = fmaxf(m, b[o]);
  }
  float sum = 0.0f;
#pragma unroll
  for (int o = 0; o < 10; ++o) {
    b[o] = __expf(b[o] - m);
    sum += b[o];
  }
  const float inv = 1.0f / sum;
#pragma unroll
  for (int o = 0; o < 10; ++o) c0b[i * 10 + o] = b[o] * inv;
}

// ---------------------------------------------------------------------------
// Pass-0 GEMM (r12 verbatim, race-fixed): s0 partials over 36 K-splits.
// ---------------------------------------------------------------------------
__global__ __launch_bounds__(256) void gemm_s0_kernel(
    const float* __restrict__ u, const float* __restrict__ cw,
    const float* __restrict__ c0b, float* __restrict__ s0p) {
  __shared__ float a_l[64 * 257];
  __shared__ float b_l[64 * 160];
  __shared__ float c0_l[320];
  const int mt = blockIdx.x;   // 0..7
  const int ks = blockIdx.y;   // 0..35
  const int m0 = mt * 64;
  const int tid = threadIdx.x;
  const int mb = tid >> 4;
  const int ob = (tid & 15) * 10;

  for (int i = tid; i < 320; i += 256) c0_l[i] = c0b[(ks * 32) * 10 + i];
  for (int idx = tid; idx < 16384; idx += 256) {
    const int m = idx >> 8, kk = idx & 255;
    a_l[m * 257 + kk] = u[(size_t)(m0 + m) * 9216 + ks * 256 + kk];
  }

  float acc[4][10];
#pragma unroll
  for (int r = 0; r < 4; ++r)
#pragma unroll
    for (int c = 0; c < 10; ++c) acc[r][c] = 0.0f;

#pragma unroll 1
  for (int kc = 0; kc < 4; ++kc) {
    __syncthreads();
    for (int idx = tid; idx < 10240; idx += 256) {
      const int kk = idx / 160, od = idx - kk * 160;
      const int kg = kc * 64 + kk;
      b_l[kk * 160 + od] = cw[((size_t)ks * 256 + kg) * 160 + od] *
                           c0_l[(kg >> 3) * 10 + (od >> 4)];
    }
    __syncthreads();
#pragma unroll 4
    for (int kk = 0; kk < 64; ++kk) {
      float a4[4];
#pragma unroll
      for (int r = 0; r < 4; ++r)
        a4[r] = a_l[(mb * 4 + r) * 257 + kc * 64 + kk];
      const float* bp_ = &b_l[kk * 160 + ob];
#pragma unroll
      for (int c = 0; c < 10; ++c) {
        const float bv = bp_[c];
#pragma unroll
        for (int r = 0; r < 4; ++r) acc[r][c] = fmaf(a4[r], bv, acc[r][c]);
      }
    }
  }

#pragma unroll
  for (int r = 0; r < 4; ++r) {
#pragma unroll
    for (int c = 0; c < 10; ++c) {
      s0p[((size_t)ks * N_IMG + m0 + mb * 4 + r) * 160 + ob + c] = acc[r][c];
    }
  }
}

// ---------------------------------------------------------------------------
// conv1 half-row worker (round-6): 10 outputs at ox' = H*10 + (0..9).
// ---------------------------------------------------------------------------
template <int H>
__device__ __forceinline__ void conv1_half(const float* __restrict__ ib,
                                           const float* __restrict__ w1l,
                                           float* __restrict__ stg, int ch,
                                           int oy, float bv1) {
  float a[10];
#pragma unroll
  for (int ox = 0; ox < 10; ++ox) a[ox] = bv1;
#pragma unroll
  for (int r = 0; r < 9; ++r) {
    float row[20];
    const float4* rp = (const float4*)&ib[(oy + r) * 28 + H * 8];
#pragma unroll
    for (int q = 0; q < 5; ++q) {
      float4 v4 = rp[q];
      row[4 * q + 0] = v4.x; row[4 * q + 1] = v4.y;
      row[4 * q + 2] = v4.z; row[4 * q + 3] = v4.w;
    }
#pragma unroll
    for (int s = 0; s < 9; ++s) {
      const float wval = w1l[ch * 81 + r * 9 + s];
#pragma unroll
      for (int ox = 0; ox < 10; ++ox)
        a[ox] = fmaf(row[ox + s + 2 * H], wval, a[ox]);
    }
  }
  float2* dst = (float2*)&stg[oy * 20 + H * 10];
#pragma unroll
  for (int q = 0; q < 5; ++q) {
    float2 v2;
    v2.x = fmaxf(a[2 * q + 0], 0.0f);
    v2.y = fmaxf(a[2 * q + 1], 0.0f);
    dst[q] = v2;
  }
}

// ---------------------------------------------------------------------------
// Fused conv1 -> hi/lo A (swizzled) -> MFMA conv2 (k-split, depth-2 B
// prefetch) -> squash.  VERBATIM round 6/9 (592 us, VGPR 120, no spill).
// ---------------------------------------------------------------------------
__global__ __launch_bounds__(512, 1) void fused_conv_kernel(
    const float* __restrict__ x, const float* __restrict__ w1,
    const float* __restrict__ b1, const unsigned short* __restrict__ bph,
    const unsigned short* __restrict__ bpl, const float* __restrict__ b2,
    float* __restrict__ u) {
  __shared__ __align__(16) char smem[115008];
  float* stg = (float*)(smem + 51776);   // [2][16][404]
  float* img = (float*)(smem + 103488);  // [2][784]
  float* w1l = (float*)(smem + 109760);  // [16*81]
  float* b1l = (float*)(smem + 114944);  // [16]
  float* mrg = (float*)smem;
  float* sq = (float*)smem;

  const int bp2 = blockIdx.x;
  const int tid = threadIdx.x;
  const int wid = tid >> 6;
  const int g = wid & 3;
  const int kpar = wid >> 2;
  const int lane = tid & 63;
  const int l15 = lane & 15;
  const int lq4 = lane >> 4;
  const int lqb = lq4 & 1;
  const int lh = lane >> 5;

  int rowb[5];
  bool okm[5];
#pragma unroll
  for (int mt = 0; mt < 5; ++mt) {
    const int m = mt * 16 + l15;
    okm[mt] = (m < 72);
    const int mm = okm[mt] ? m : 0;
    const int im = (mm >= 36) ? 1 : 0;
    const int p = mm - 36 * im;
    const int oy = p / 6, ox = p - 6 * oy;
    rowb[mt] = im * 400 + 40 * oy + 2 * ox;
  }

  for (int i = tid; i < 1568; i += 512) img[i] = x[bp2 * 1568 + i];
  if (tid < 16) {  // zero pad-slot 800 (swz 804) in all 4 arrays
    *(int*)(smem + (tid >> 2) * 12944 + 804 * 16 + (tid & 3) * 4) = 0;
  }

  f32x4 acc[5][4];
#pragma unroll
  for (int mt = 0; mt < 5; ++mt)
#pragma unroll
    for (int nn = 0; nn < 4; ++nn) acc[mt][nn] = (f32x4){0.f, 0.f, 0.f, 0.f};

  const char* hbase = smem + lqb * 12944;
  const char* lbase = smem + 25888 + lqb * 12944;
  const int tt0 = kpar ? 21 : 0;
  const int tt1 = kpar ? 41 : 21;
  const int nk = tt1 - tt0;

#define MFMA_STEP(CBH, CBL, J, DOPF)                                       \
  {                                                                        \
    const int rs_ = 2 * (tt0 + (J)) + lh;                                  \
    const int r_ = (rs_ * 57) >> 9;                                        \
    const int s_ = rs_ - 9 * r_;                                           \
    const int rs20_ = 20 * r_ + s_;                                        \
    const bool okrs_ = (rs_ <= 80);                                        \
    bf16x8 ah[5], al[5];                                                   \
    _Pragma("unroll") for (int mt = 0; mt < 5; ++mt) {                     \
      const int row_ = (okm[mt] && okrs_) ? (rowb[mt] + rs20_) : 800;      \
      const int ad_ = swz16(row_);                                         \
      ah[mt] = *(const bf16x8*)(hbase + ad_);                              \
      al[mt] = *(const bf16x8*)(lbase + ad_);                              \
    }                                                                      \
    _Pragma("unroll") for (int mt = 0; mt < 5; ++mt) {                     \
      _Pragma("unroll") for (int nn = 0; nn < 4; ++nn) {                   \
        acc[mt][nn] = __builtin_amdgcn_mfma_f32_16x16x32_bf16(             \
            al[mt], CBH[nn], acc[mt][nn], 0, 0, 0);                        \
        acc[mt][nn] = __builtin_amdgcn_mfma_f32_16x16x32_bf16(             \
            ah[mt], CBL[nn], acc[mt][nn], 0, 0, 0);                        \
        acc[mt][nn] = __builtin_amdgcn_mfma_f32_16x16x32_bf16(             \
            ah[mt], CBH[nn], acc[mt][nn], 0, 0, 0);                        \
      }                                                                    \
    }                                                                      \
    if ((DOPF) && (J) + 2 < nk) {                                          \
      _Pragma("unroll") for (int nn = 0; nn < 4; ++nn) {                   \
        CBH[nn] = *(const bf16x8*)(pb[nn] + (size_t)((J) + 2) * 512);      \
        CBL[nn] = *(const bf16x8*)(pl[nn] + (size_t)((J) + 2) * 512);      \
      }                                                                    \
    }                                                                      \
  }

#pragma unroll 1
  for (int c = 0; c < 16; ++c) {
    const unsigned short* pb[4];
    const unsigned short* pl[4];
#pragma unroll
    for (int nn = 0; nn < 4; ++nn) {
      const size_t base =
          ((size_t)(g * 4 + nn) * 656 + c * 41 + tt0) * 512 + lane * 8;
      pb[nn] = bph + base;
      pl[nn] = bpl + base;
    }
    bf16x8 cbh0[4], cbl0[4], cbh1[4], cbl1[4];
#pragma unroll
    for (int nn = 0; nn < 4; ++nn) {
      cbh0[nn] = *(const bf16x8*)(pb[nn]);
      cbl0[nn] = *(const bf16x8*)(pl[nn]);
      cbh1[nn] = *(const bf16x8*)(pb[nn] + 512);
      cbl1[nn] = *(const bf16x8*)(pl[nn] + 512);
    }

    __syncthreads();
    for (int i = tid; i < 1296; i += 512) w1l[i] = w1[c * 1296 + i];
    if (tid < 16) b1l[tid] = b1[c * 16 + tid];
    __syncthreads();

    for (int t = tid; t < 1280; t += 512) {
      const int half = (t >= 640) ? 1 : 0;
      const int rest = t - half * 640;
      const int ig = rest / 320;
      const int r2 = rest - ig * 320;
      const int ch = r2 & 15;
      const int oy = r2 >> 4;
      const float* ib = &img[ig * 784];
      float* sb = &stg[(ig * 16 + ch) * 404];
      const float bv1 = b1l[ch];
      if (half == 0)
        conv1_half<0>(ib, w1l, sb, ch, oy, bv1);
      else
        conv1_half<1>(ib, w1l, sb, ch, oy, bv1);
    }
    __syncthreads();

    for (int t = tid; t < 800; t += 512) {
      const int ig = t / 400;
      const int pos = t - ig * 400;
      const int ad = swz16(t);
      unsigned int hw[8], lw[8];
#pragma unroll
      for (int jp = 0; jp < 8; ++jp) {
        unsigned short h2[2], l2[2];
#pragma unroll
        for (int e = 0; e < 2; ++e) {
          const float v = stg[(ig * 16 + jp * 2 + e) * 404 + pos];
          const unsigned short hh = f2bf(v);
          h2[e] = hh;
          l2[e] = f2bf(v - bf2f(hh));
        }
        hw[jp] = (unsigned int)h2[0] | ((unsigned int)h2[1] << 16);
        lw[jp] = (unsigned int)l2[0] | ((unsigned int)l2[1] << 16);
      }
      *(u32x4*)(smem + ad) = (u32x4){hw[0], hw[1], hw[2], hw[3]};
      *(u32x4*)(smem + 12944 + ad) = (u32x4){hw[4], hw[5], hw[6], hw[7]};
      *(u32x4*)(smem + 25888 + ad) = (u32x4){lw[0], lw[1], lw[2], lw[3]};
      *(u32x4*)(smem + 38832 + ad) = (u32x4){lw[4], lw[5], lw[6], lw[7]};
    }
    __syncthreads();

    int j = 0;
#pragma unroll 1
    for (; j + 1 < nk; j += 2) {
      MFMA_STEP(cbh0, cbl0, j, 1);
      MFMA_STEP(cbh1, cbl1, j + 1, 1);
    }
    if (j < nk) MFMA_STEP(cbh0, cbl0, j, 0);
  }
#undef MFMA_STEP

  __syncthreads();
  if (kpar == 1) {
#pragma unroll
    for (int mt = 0; mt < 5; ++mt)
#pragma unroll
      for (int nn = 0; nn < 4; ++nn)
        *(f32x4*)(mrg + ((((g * 5 + mt) * 4 + nn) * 64 + lane) << 2)) =
            acc[mt][nn];
  }
  __syncthreads();
  if (kpar == 0) {
#pragma unroll
    for (int mt = 0; mt < 5; ++mt)
#pragma unroll
      for (int nn = 0; nn < 4; ++nn)
        acc[mt][nn] +=
            *(const f32x4*)(mrg + ((((g * 5 + mt) * 4 + nn) * 64 + lane) << 2));
  }
  __syncthreads();
  if (kpar == 0) {
    float b2v[4];
#pragma unroll
    for (int nn = 0; nn < 4; ++nn) b2v[nn] = b2[(g * 4 + nn) * 16 + l15];
#pragma unroll
    for (int mt = 0; mt < 5; ++mt) {
#pragma unroll
      for (int i = 0; i < 4; ++i) {
        const int m = mt * 16 + lq4 * 4 + i;
        if (m < 72) {
          const int im = (m >= 36) ? 1 : 0;
          const int p36 = m - 36 * im;
#pragma unroll
          for (int nn = 0; nn < 4; ++nn) {
            sq[(im * 256 + (g * 4 + nn) * 16 + l15) * 36 + p36] =
                acc[mt][nn][i] + b2v[nn];
          }
        }
      }
    }
  }
  __syncthreads();

  for (int i = tid; i < 2304; i += 512) {
    const int ig = i / 1152;
    const int cap = i - ig * 1152;
    const int gg = cap / 36, yx = cap - 36 * gg;
    float vals[8];
    float lensq = 0.0f;
#pragma unroll
    for (int d = 0; d < 8; ++d) {
      vals[d] = sq[(ig * 256 + gg * 8 + d) * 36 + yx];
      lensq = fmaf(vals[d], vals[d], lensq);
    }
    const float len = sqrtf(lensq);
    const float scale = lensq / (1.0f + lensq) / len;
    float4* dst = (float4*)(u + ((size_t)(bp2 * 2 + ig) * 1152 + cap) * 8);
    float4 lo4, hi4;
    lo4.x = vals[0] * scale; lo4.y = vals[1] * scale;
    lo4.z = vals[2] * scale; lo4.w = vals[3] * scale;
    hi4.x = vals[4] * scale; hi4.y = vals[5] * scale;
    hi4.z = vals[6] * scale; hi4.w = vals[7] * scale;
    dst[0] = lo4; dst[1] = hi4;
  }
}

// ---------------------------------------------------------------------------
// routing pass A (passes 1-3): 4 images/block, 32-cap chunk as 2x16 subchunks.
// Each cwt float4-pair read serves 4 images (L2 traffic /4). Phases mirror
// the r5 structure; uhat rows padded to 161 for bank spread. Partial s
// accumulated over the 2 subchunks -> s_part[36][512][160].
// ---------------------------------------------------------------------------
__global__ __launch_bounds__(256) void routing_a_kernel(
    const float* __restrict__ u, const float* __restrict__ cwt,
    const float* __restrict__ b_prior, const float* __restrict__ vsum,
    float* __restrict__ s_part) {
  __shared__ float u_l[RG * 16 * 8];     // 512 f (per subchunk)
  __shared__ float uhat[RG][16][161];    // 10304 f
  __shared__ float v_l[RG * 160];        // 640 f
  __shared__ float bp_l[32 * 10];        // 320 f
  __shared__ float c_l[RG * 16 * 10];    // 640 f
  __shared__ float s_acc[RG * 160];      // 640 f   -> total ~52.2 KB

  const int gb = blockIdx.x;  // image group (4 images)
  const int ch = blockIdx.y;  // 32-cap chunk (0..35)
  const int cap0 = ch * 32;
  const int b0 = gb * RG;
  const int tid = threadIdx.x;

  for (int i = tid; i < RG * 160; i += 256) {
    const int g = i / 160, od = i - g * 160;
    v_l[i] = vsum[(b0 + g) * 160 + od];
    s_acc[i] = 0.0f;
  }
  for (int i = tid; i < 320; i += 256) bp_l[i] = b_prior[cap0 * 10 + i];

#pragma unroll 1
  for (int cc = 0; cc < 2; ++cc) {
    const int c16 = cap0 + cc * 16;
    __syncthreads();  // prev subchunk's uhat/u_l reads done (or prologue)
    for (int i = tid; i < RG * 128; i += 256) {
      const int g = i >> 7, off = i & 127;
      u_l[g * 128 + off] = u[((size_t)(b0 + g) * 1152 + c16) * 8 + off];
    }
    __syncthreads();

    // uhat for 16 caps x 160 od x 4 images; weights read once per (i,od)
    for (int e = tid; e < 2560; e += 256) {
      const int i = e / 160, od = e - i * 160;
      const float4* wp =
          (const float4*)(cwt + ((size_t)(c16 + i) * 160 + od) * 8);
      const float4 wa = wp[0], wb = wp[1];
#pragma unroll
      for (int g = 0; g < RG; ++g) {
        const float* up = &u_l[(g * 16 + i) * 8];
        float a = up[0] * wa.x;
        a = fmaf(up[1], wa.y, a);
        a = fmaf(up[2], wa.z, a);
        a = fmaf(up[3], wa.w, a);
        a = fmaf(up[4], wb.x, a);
        a = fmaf(up[5], wb.y, a);
        a = fmaf(up[6], wb.z, a);
        a = fmaf(up[7], wb.w, a);
        uhat[g][i][od] = a;
      }
    }
    __syncthreads();

    // b = bp + uhat.vsum  (linearity of logit update), into c_l
    for (int e = tid; e < RG * 160; e += 256) {
      const int g = e / 160;
      const int r = e - g * 160;
      const int i = r / 10, o = r - i * 10;
      float agg = 0.0f;
#pragma unroll
      for (int d = 0; d < 16; ++d)
        agg = fmaf(uhat[g][i][o * 16 + d], v_l[g * 160 + o * 16 + d], agg);
      c_l[e] = bp_l[(cc * 16 + i) * 10 + o] + agg;
    }
    __syncthreads();

    // softmax per (g, cap) in-place on c_l
    if (tid < RG * 16) {
      const int g = tid >> 4, i = tid & 15;
      float bb[10];
      float m = -1e30f;
#pragma unroll
      for (int o = 0; o < 10; ++o) {
        bb[o] = c_l[(g * 16 + i) * 10 + o];
        m = fmaxf(m, bb[o]);
      }
      float sum = 0.0f;
#pragma unroll
      for (int o = 0; o < 10; ++o) {
        bb[o] = __expf(bb[o] - m);
        sum += bb[o];
      }
      const float inv = 1.0f / sum;
#pragma unroll
      for (int o = 0; o < 10; ++o) c_l[(g * 16 + i) * 10 + o] = bb[o] * inv;
    }
    __syncthreads();

    // accumulate partial s over this subchunk's 16 caps
    for (int e = tid; e < RG * 160; e += 256) {
      const int g = e / 160, od = e - g * 160;
      const int o = od >> 4;
      float a = 0.0f;
#pragma unroll
      for (int i = 0; i < 16; ++i)
        a = fmaf(c_l[(g * 16 + i) * 10 + o], uhat[g][i][od], a);
      s_acc[e] += a;
    }
  }
  __syncthreads();

  for (int e = tid; e < RG * 160; e += 256) {
    const int g = e / 160, od = e - g * 160;
    s_part[((size_t)ch * N_IMG + b0 + g) * 160 + od] = s_acc[e];
  }
}

// ---------------------------------------------------------------------------
// routing pass B: reduce nchunk partials -> squash -> v, probs; vsum mode.
// ---------------------------------------------------------------------------
__global__ __launch_bounds__(192) void routing_b_kernel(
    const float* __restrict__ s_part, int nchunk, float* __restrict__ v_out,
    float* __restrict__ probs, float* __restrict__ vsum, int mode) {
  __shared__ float s_l[160];
  __shared__ float scale_l[10];
  __shared__ float len_l[10];
  const int b = blockIdx.x;
  const int t = threadIdx.x;
  if (t < 160) {
    float a = 0.0f;
    for (int ch = 0; ch < nchunk; ++ch)
      a += s_part[((size_t)ch * N_IMG + b) * 160 + t];
    s_l[t] = a;
  }
  __syncthreads();
  if (t < 10) {
    float lensq = 0.0f;
#pragma unroll
    for (int d = 0; d < 16; ++d) {
      const float xv = s_l[t * 16 + d];
      lensq = fmaf(xv, xv, lensq);
    }
    const float len = sqrtf(lensq);
    scale_l[t] = lensq / (1.0f + lensq) / len;
    len_l[t] = lensq / (1.0f + lensq);
  }
  __syncthreads();
  if (t < 160) {
    const float vv = s_l[t] * scale_l[t / 16];
    v_out[b * 160 + t] = vv;
    if (mode == 0) vsum[b * 160 + t] = vv;
    else if (mode == 1) vsum[b * 160 + t] += vv;
  }
  if (t < 10) probs[b * 10 + t] = len_l[t];
}

// ===========================================================================
extern "C" void kernel_launch(void* const* d_in, const int* in_sizes, int n_in,
                              void* d_out, int out_size, void* d_ws,
                              size_t ws_size, hipStream_t stream) {
  const float* x  = (const float*)d_in[0];
  const float* w1 = (const float*)d_in[1];
  const float* b1 = (const float*)d_in[2];
  const float* w2 = (const float*)d_in[3];
  const float* b2 = (const float*)d_in[4];
  const float* cw = (const float*)d_in[5];
  const float* bp = (const float*)d_in[6];

  float* out = (float*)d_out;
  float* v_out = out;                // [512,10,16]
  float* probs = out + N_IMG * 160;  // [512,10]

  float* base = (float*)d_ws;
  unsigned short* bph = (unsigned short*)d_ws;         // float [0, 2686976)
  unsigned short* bpl = bph + (size_t)16 * 656 * 512;  // float [2686976, 5373952)
  float* u    = base + 5373952;                        // 4718592 floats
  float* vsum = u + 4718592;                           // 81920 floats
  float* c0b  = vsum + 81920;                          // 11520 floats
  // Aliases into the bph/bpl region (dead after fused_conv):
  float* cwt = base;            // [0, 1474560)
  float* sp  = base + 1474560;  // [1474560, 4423680) — 36*512*160 (s0p & sp)

  repack_b_kernel<<<dim3(16, 16), 256, 0, stream>>>(w2, bph, bpl);
  fused_conv_kernel<<<256, 512, 0, stream>>>(x, w1, b1, bph, bpl, b2, u);
  // pass 0 as GEMM (c0 is image-independent)
  c0_kernel<<<5, 256, 0, stream>>>(bp, c0b);
  repack_cw_kernel<<<1152, 160, 0, stream>>>(cw, cwt);
  gemm_s0_kernel<<<dim3(8, 36), 256, 0, stream>>>(u, cw, c0b, sp);
  routing_b_kernel<<<N_IMG, 192, 0, stream>>>(sp, 36, v_out, probs, vsum, 0);
  // passes 1..3 (4 images/block; sp region reused)
  for (int pass = 1; pass < 4; ++pass) {
    const int mode = (pass < 3) ? 1 : 2;
    routing_a_kernel<<<dim3(N_IMG / RG, 36), 256, 0, stream>>>(u, cwt, bp,
                                                               vsum, sp);
    routing_b_kernel<<<N_IMG, 192, 0, stream>>>(sp, 36, v_out, probs, vsum,
                                                mode);
  }
}